// Round 2
// baseline (284.242 us; speedup 1.0000x reference)
//
#include <hip/hip_runtime.h>
#include <math.h>

typedef __attribute__((ext_vector_type(8))) short short8x;   // 8 x bf16 = 4 VGPRs
typedef __attribute__((ext_vector_type(4))) float float4x;   // MFMA 16x16 C/D frag
typedef unsigned short u16;
typedef unsigned int u32;

__device__ __forceinline__ float bf2f(u16 u) {
    return __uint_as_float(((u32)u) << 16);
}
__device__ __forceinline__ u16 f2bf(float f) {
    u32 u = __float_as_uint(f);
    u32 r = (u + 0x7fffu + ((u >> 16) & 1u)) >> 16;   // round-to-nearest-even
    return (u16)r;
}

// ---------------------------------------------------------------- sizes
// B=4, H=W=96, C_in=64, C_hid=256, C_out=64, padded HP=98 (zero border)
// All global inputs/outputs are fp32 (reference dtype). Internals bf16.
// ws layout (bytes):
//   xT   @ 0         : 4*96*96*64*2        = 4,718,592   x transposed -> bf16 c-minor
//   h2p  @ 4718592   : 4*98*98*256*2       = 19,668,992  gelu(fc1) padded, bf16 c-minor
//   W1A  @ 24387584  : 4*256*64*2          = 131,072     dyn fc1 weight bf16 [b][oc][c]
//   W2A  @ 24518656  : 4*9*64*256*2        = 1,179,648   dyn fc2 weight bf16 [b][k][oc][c]
//   gl1  @ 25698304  : 4*64*4              = 1,024       fp32
//   gl2  @ 25699328  : 4*256*9*4           = 36,864      fp32

__global__ __launch_bounds__(256) void k_zero(u32* p, int n) {
    int i = blockIdx.x * 256 + threadIdx.x;
    int stride = gridDim.x * 256;
    for (; i < n; i += stride) p[i] = 0u;
}

// x[b][c][y][x] (fp32) -> xT[b][y][x][c] (bf16)   (c_in = 64)
__global__ __launch_bounds__(256) void k_transpose(const float* __restrict__ x, u16* __restrict__ xT) {
    int b = blockIdx.x / 96, y = blockIdx.x % 96;
    __shared__ u16 lds[64][96];
    const float* xr = x + ((b * 64) * 96 + y) * 96;   // stride between c: 96*96
    for (int idx = threadIdx.x; idx < 64 * 96; idx += 256) {
        int c = idx / 96, xx = idx - c * 96;
        lds[c][xx] = f2bf(xr[c * 96 * 96 + xx]);
    }
    __syncthreads();
    u16* o = xT + ((b * 96 + y) * 96) * 64;
    for (int idx = threadIdx.x; idx < 96 * 64; idx += 256) {
        int xx = idx >> 6, c = idx & 63;
        o[idx] = lds[c][xx];
    }
}

// global max over image per (b,c), fp32 input
__global__ __launch_bounds__(256) void k_gl1(const float* __restrict__ x, float* __restrict__ gl1) {
    int b = blockIdx.x >> 6, c = blockIdx.x & 63;
    const float* p = x + (b * 64 + c) * 9216;
    float m = -1e30f;
    for (int i = threadIdx.x; i < 9216; i += 256) m = fmaxf(m, p[i]);
    __shared__ float red[256];
    red[threadIdx.x] = m;
    __syncthreads();
    for (int s = 128; s > 0; s >>= 1) {
        if (threadIdx.x < s) red[threadIdx.x] = fmaxf(red[threadIdx.x], red[threadIdx.x + s]);
        __syncthreads();
    }
    if (threadIdx.x == 0) gl1[b * 64 + c] = red[0];
}

// fc1 gating -> W1A[b][oc=256][c=64] = sigmoid(out1[c] + ocp[oc]) * w1[oc][c]
__global__ __launch_bounds__(256) void k_gate1(const float* __restrict__ gl1,
                                               const float* __restrict__ ce, const float* __restrict__ gd,
                                               const float* __restrict__ gd2, const float* __restrict__ ci,
                                               const float* __restrict__ w1, u16* __restrict__ W1A) {
    int b = blockIdx.x, t = threadIdx.x;
    __shared__ float rce[64], out1[64], ocp[256];
    float cew = ce[0], gdw = gd[0], gd2w = gd2[0];
    if (t < 64) {
        float r = fmaxf(gl1[b * 64 + t] * cew, 0.f);
        rce[t] = r;
        out1[t] = r * gdw;
    }
    __syncthreads();
    {   // t = oc = p*32 + oi
        int p = t >> 5, oi = t & 31;
        float s = 0.f;
        #pragma unroll
        for (int g = 0; g < 8; g++) s += rce[p * 8 + g] * ci[oi * 8 + g];
        ocp[t] = fmaxf(s, 0.f) * gd2w;
    }
    __syncthreads();
    u16* Wb = W1A + b * 256 * 64;
    for (int idx = t; idx < 256 * 64; idx += 256) {
        int o = idx >> 6, c = idx & 63;
        float v = out1[c] + ocp[o];
        float sg = 1.f / (1.f + expf(-v));
        Wb[idx] = f2bf(sg * w1[idx]);
    }
}

// h2p interior = gelu( W1A[b] (256x64) @ xT[b] (64 x 9216) ), one row y per block
__global__ __launch_bounds__(256) void k_gemm1(const u16* __restrict__ W1A, const u16* __restrict__ xT,
                                               u16* __restrict__ h2p) {
    int b = blockIdx.x / 96, y = blockIdx.x % 96;
    int t = threadIdx.x, wave = t >> 6, lane = t & 63, l15 = lane & 15, quad = lane >> 4;
    float4x acc[4][6];
    #pragma unroll
    for (int mt = 0; mt < 4; mt++)
        #pragma unroll
        for (int nt = 0; nt < 6; nt++) acc[mt][nt] = (float4x){0.f, 0.f, 0.f, 0.f};
    const u16* Wb = W1A + b * 256 * 64;
    const u16* xb = xT + ((b * 96 + y) * 96) * 64;
    #pragma unroll
    for (int c0 = 0; c0 < 64; c0 += 32) {
        short8x bfr[6];
        #pragma unroll
        for (int nt = 0; nt < 6; nt++) {
            int xx = nt * 16 + l15;
            bfr[nt] = *(const short8x*)(xb + xx * 64 + c0 + quad * 8);
        }
        #pragma unroll
        for (int mt = 0; mt < 4; mt++) {
            int oc = wave * 64 + mt * 16 + l15;
            short8x afr = *(const short8x*)(Wb + oc * 64 + c0 + quad * 8);
            #pragma unroll
            for (int nt = 0; nt < 6; nt++)
                acc[mt][nt] = __builtin_amdgcn_mfma_f32_16x16x32_bf16(afr, bfr[nt], acc[mt][nt], 0, 0, 0);
        }
    }
    const float is2 = 0.70710678118654752f;
    #pragma unroll
    for (int mt = 0; mt < 4; mt++) {
        #pragma unroll
        for (int nt = 0; nt < 6; nt++) {
            int xx = nt * 16 + l15;
            int oc0 = wave * 64 + mt * 16 + quad * 4;
            u16 pk[4];
            #pragma unroll
            for (int r = 0; r < 4; r++) {
                float v = acc[mt][nt][r];
                float g = 0.5f * v * (1.f + erff(v * is2));   // exact GELU
                pk[r] = f2bf(g);
            }
            u16* dst = h2p + ((b * 98 + y + 1) * 98 + (xx + 1)) * 256 + oc0;
            *(ushort4*)dst = make_ushort4(pk[0], pk[1], pk[2], pk[3]);
        }
    }
}

// 3x3 adaptive max pool over h (32x32 bins), read from padded c-minor h2p (bf16)
__global__ __launch_bounds__(256) void k_gl2(const u16* __restrict__ h2p, float* __restrict__ gl2) {
    int b = blockIdx.x / 9, k = blockIdx.x % 9;
    int ki = k / 3, kj = k - ki * 3;
    int c = threadIdx.x;
    float m = -1e30f;
    for (int r = 0; r < 32; r++) {
        int row = ki * 32 + r + 1;
        const u16* base = h2p + ((b * 98 + row) * 98 + (kj * 32 + 1)) * 256 + c;
        for (int p = 0; p < 32; p++) m = fmaxf(m, bf2f(base[p * 256]));
    }
    gl2[(b * 256 + c) * 9 + k] = m;
}

// fc2 gating -> W2A[b][k=9][oc=64][c=256] = sigmoid(out2[c][k] + ocp2[o][k]) * w2[o][c][k]
__global__ __launch_bounds__(256) void k_gate2(const float* __restrict__ gl2,
                                               const float* __restrict__ ce, const float* __restrict__ gd,
                                               const float* __restrict__ gd2, const float* __restrict__ ci,
                                               const float* __restrict__ w2, u16* __restrict__ W2A) {
    int b = blockIdx.x, t = threadIdx.x;
    __shared__ float rce[256][5];
    __shared__ float out2[256][9];
    __shared__ float ocp2[64][9];
    {
        float gl[9], r[5];
        const float* g = gl2 + (b * 256 + t) * 9;
        #pragma unroll
        for (int k = 0; k < 9; k++) gl[k] = g[k];
        #pragma unroll
        for (int n = 0; n < 5; n++) {
            float s = 0.f;
            #pragma unroll
            for (int k = 0; k < 9; k++) s += gl[k] * ce[n * 9 + k];
            r[n] = fmaxf(s, 0.f);
            rce[t][n] = r[n];
        }
        #pragma unroll
        for (int k = 0; k < 9; k++) {
            float s = 0.f;
            #pragma unroll
            for (int n = 0; n < 5; n++) s += r[n] * gd[k * 5 + n];
            out2[t][k] = s;
        }
    }
    __syncthreads();
    if (t < 64) {
        int p = t >> 1, oi = t & 1;
        float rt[5];
        #pragma unroll
        for (int n = 0; n < 5; n++) {
            float s = 0.f;
            #pragma unroll
            for (int g = 0; g < 8; g++) s += rce[p * 8 + g][n] * ci[oi * 8 + g];
            rt[n] = fmaxf(s, 0.f);
        }
        #pragma unroll
        for (int k = 0; k < 9; k++) {
            float s = 0.f;
            #pragma unroll
            for (int n = 0; n < 5; n++) s += rt[n] * gd2[k * 5 + n];
            ocp2[t][k] = s;
        }
    }
    __syncthreads();
    u16* Wb = W2A + b * 9 * 64 * 256;
    for (int idx = t; idx < 9 * 64 * 256; idx += 256) {
        int c = idx & 255;
        int o = (idx >> 8) & 63;
        int k = idx >> 14;
        float v = out2[c][k] + ocp2[o][k];
        float sg = 1.f / (1.f + expf(-v));
        Wb[idx] = f2bf(sg * w2[(o * 256 + c) * 9 + k]);
    }
}

// out[b][oc][y][x] (fp32) = sum_{k=(i,j), c} W2A[b][k][oc][c] * h2p[b][y+i][x+j][c]
// one row y per block; 4 waves split 2x2 over (M=64, N=96)
__global__ __launch_bounds__(256) void k_conv2(const u16* __restrict__ W2A, const u16* __restrict__ h2p,
                                               float* __restrict__ out) {
    int b = blockIdx.x / 96, y = blockIdx.x % 96;
    int t = threadIdx.x, wave = t >> 6, lane = t & 63, l15 = lane & 15, quad = lane >> 4;
    int mi = wave & 1, ni = wave >> 1;   // mi: 32-oc half, ni: 48-px half
    float4x acc[2][3];
    #pragma unroll
    for (int mt = 0; mt < 2; mt++)
        #pragma unroll
        for (int nt = 0; nt < 3; nt++) acc[mt][nt] = (float4x){0.f, 0.f, 0.f, 0.f};
    const u16* Wb = W2A + b * 9 * 64 * 256;
    for (int c0 = 0; c0 < 256; c0 += 32) {
        #pragma unroll
        for (int i = 0; i < 3; i++) {
            const u16* hrow = h2p + ((b * 98 + y + i) * 98) * 256;
            #pragma unroll
            for (int j = 0; j < 3; j++) {
                int k = i * 3 + j;
                short8x af[2];
                #pragma unroll
                for (int mt = 0; mt < 2; mt++) {
                    int oc = mi * 32 + mt * 16 + l15;
                    af[mt] = *(const short8x*)(Wb + (k * 64 + oc) * 256 + c0 + quad * 8);
                }
                #pragma unroll
                for (int nt = 0; nt < 3; nt++) {
                    int p = ni * 48 + nt * 16 + l15 + j;
                    short8x bf = *(const short8x*)(hrow + p * 256 + c0 + quad * 8);
                    #pragma unroll
                    for (int mt = 0; mt < 2; mt++)
                        acc[mt][nt] = __builtin_amdgcn_mfma_f32_16x16x32_bf16(af[mt], bf, acc[mt][nt], 0, 0, 0);
                }
            }
        }
    }
    #pragma unroll
    for (int mt = 0; mt < 2; mt++) {
        #pragma unroll
        for (int nt = 0; nt < 3; nt++) {
            int xx = ni * 48 + nt * 16 + l15;
            #pragma unroll
            for (int r = 0; r < 4; r++) {
                int oc = mi * 32 + mt * 16 + quad * 4 + r;
                out[((b * 64 + oc) * 96 + y) * 96 + xx] = acc[mt][nt][r];
            }
        }
    }
}

extern "C" void kernel_launch(void* const* d_in, const int* in_sizes, int n_in,
                              void* d_out, int out_size, void* d_ws, size_t ws_size,
                              hipStream_t stream) {
    const float* x    = (const float*)d_in[0];
    const float* w1   = (const float*)d_in[1];
    const float* ce1  = (const float*)d_in[2];
    const float* gd1  = (const float*)d_in[3];
    const float* gd21 = (const float*)d_in[4];
    const float* ci1  = (const float*)d_in[5];
    const float* w2   = (const float*)d_in[6];
    const float* ce2  = (const float*)d_in[7];
    const float* gd2  = (const float*)d_in[8];
    const float* gd22 = (const float*)d_in[9];
    const float* ci2  = (const float*)d_in[10];
    float* out = (float*)d_out;

    char* ws = (char*)d_ws;
    u16*   xT  = (u16*)(ws + 0);
    u16*   h2p = (u16*)(ws + 4718592);
    u16*   W1A = (u16*)(ws + 24387584);
    u16*   W2A = (u16*)(ws + 24518656);
    float* gl1 = (float*)(ws + 25698304);
    float* gl2 = (float*)(ws + 25699328);

    k_zero     <<<2048, 256, 0, stream>>>((u32*)h2p, 19668992 / 4);
    k_transpose<<<384,  256, 0, stream>>>(x, xT);
    k_gl1      <<<256,  256, 0, stream>>>(x, gl1);
    k_gate1    <<<4,    256, 0, stream>>>(gl1, ce1, gd1, gd21, ci1, w1, W1A);
    k_gemm1    <<<384,  256, 0, stream>>>(W1A, xT, h2p);
    k_gl2      <<<36,   256, 0, stream>>>(h2p, gl2);
    k_gate2    <<<4,    256, 0, stream>>>(gl2, ce2, gd2, gd22, ci2, w2, W2A);
    k_conv2    <<<384,  256, 0, stream>>>(W2A, h2p, out);
}

// Round 3
// 179.553 us; speedup vs baseline: 1.5831x; 1.5831x over previous
//
#include <hip/hip_runtime.h>
#include <math.h>

typedef __attribute__((ext_vector_type(8))) short short8x;   // 8 x bf16 = 4 VGPRs
typedef __attribute__((ext_vector_type(4))) float float4x;   // MFMA 16x16 C/D frag
typedef unsigned short u16;
typedef unsigned int u32;

__device__ __forceinline__ float bf2f(u16 u) {
    return __uint_as_float(((u32)u) << 16);
}
__device__ __forceinline__ u16 f2bf(float f) {
    u32 u = __float_as_uint(f);
    u32 r = (u + 0x7fffu + ((u >> 16) & 1u)) >> 16;   // round-to-nearest-even
    return (u16)r;
}

// ---------------------------------------------------------------- sizes
// B=4, H=W=96, C_in=64, C_hid=256, C_out=64, padded HP=98. c split: 8 groups x 32.
// ws layout (bytes):
//   xT    @ 0         : 4*96*96*64*2  = 4,718,592  x -> bf16 c-minor [b][y][x][64]
//       (region reused AFTER k_gemm1 by gl2p/out2g/ocp2g — temporally disjoint)
//   gl2p  @ 0         : 4*9*8*256*4   = 294,912    fp32 partial max [b][k][rg][256]
//   out2g @ 294912    : 4*256*9*4     = 36,864     fp32
//   ocp2g @ 331776    : 4*64*9*4      = 9,216      fp32
//   h2p   @ 4718592   : 4*8*98*98*32*2= 19,668,992 bf16 [b][g][98][98][32]
//   W1A   @ 24387584  : 4*256*64*2    = 131,072    bf16 [b][oc][c64]
//   W2A   @ 24518656  : 4*8*9*64*32*2 = 1,179,648  bf16 [b][g][k][oc][c32]
//   gl1   @ 25698304  : 4*64*4        = 1,024      fp32

// zero ONLY the h2p border (interior fully overwritten by k_gemm1)
// grid 32 = (b*8+g); plane = [98][98][32] u16
__global__ __launch_bounds__(256) void k_border(u32* __restrict__ h2p32) {
    u32* plane = h2p32 + blockIdx.x * (98 * 98 * 16);   // u32 units
    int t = threadIdx.x;
    for (int i = t; i < 1568; i += 256) plane[i] = 0u;                    // row 0
    for (int i = t; i < 1568; i += 256) plane[97 * 98 * 16 + i] = 0u;     // row 97
    for (int i = t; i < 3072; i += 256) {                                 // cols 0 & 97
        int r = (i >> 5) + 1;
        int p = ((i >> 4) & 1) * 97;
        int w = i & 15;
        plane[(r * 98 + p) * 16 + w] = 0u;
    }
}

// x[b][c][y][x] (fp32) -> xT[b][y][x][c] (bf16), bank-conflict-free
__global__ __launch_bounds__(256) void k_transpose(const float* __restrict__ x, u16* __restrict__ xT) {
    int b = blockIdx.x / 96, y = blockIdx.x % 96;
    __shared__ float lds[64][97];
    const float* xr = x + ((b * 64) * 96 + y) * 96;
    for (int idx = threadIdx.x; idx < 64 * 96; idx += 256) {
        int c = idx / 96, xx = idx - c * 96;
        lds[c][xx] = xr[c * 96 * 96 + xx];
    }
    __syncthreads();
    u16* o = xT + ((b * 96 + y) * 96) * 64;
    for (int idx = threadIdx.x; idx < 96 * 64; idx += 256) {
        int xx = idx >> 6, c = idx & 63;
        o[idx] = f2bf(lds[c][xx]);
    }
}

// global max over image per (b,c), fp32 input
__global__ __launch_bounds__(256) void k_gl1(const float* __restrict__ x, float* __restrict__ gl1) {
    int b = blockIdx.x >> 6, c = blockIdx.x & 63;
    const float* p = x + (b * 64 + c) * 9216;
    float m = -1e30f;
    for (int i = threadIdx.x; i < 9216; i += 256) m = fmaxf(m, p[i]);
    __shared__ float red[256];
    red[threadIdx.x] = m;
    __syncthreads();
    for (int s = 128; s > 0; s >>= 1) {
        if (threadIdx.x < s) red[threadIdx.x] = fmaxf(red[threadIdx.x], red[threadIdx.x + s]);
        __syncthreads();
    }
    if (threadIdx.x == 0) gl1[b * 64 + c] = red[0];
}

// fc1 gating -> W1A[b][oc=256][c=64]
__global__ __launch_bounds__(256) void k_gate1(const float* __restrict__ gl1,
                                               const float* __restrict__ ce, const float* __restrict__ gd,
                                               const float* __restrict__ gd2, const float* __restrict__ ci,
                                               const float* __restrict__ w1, u16* __restrict__ W1A) {
    int b = blockIdx.x, t = threadIdx.x;
    __shared__ float rce[64], out1[64], ocp[256];
    float cew = ce[0], gdw = gd[0], gd2w = gd2[0];
    if (t < 64) {
        float r = fmaxf(gl1[b * 64 + t] * cew, 0.f);
        rce[t] = r;
        out1[t] = r * gdw;
    }
    __syncthreads();
    {
        int p = t >> 5, oi = t & 31;
        float s = 0.f;
        #pragma unroll
        for (int g = 0; g < 8; g++) s += rce[p * 8 + g] * ci[oi * 8 + g];
        ocp[t] = fmaxf(s, 0.f) * gd2w;
    }
    __syncthreads();
    u16* Wb = W1A + b * 256 * 64;
    for (int idx = t; idx < 256 * 64; idx += 256) {
        int o = idx >> 6, c = idx & 63;
        float v = out1[c] + ocp[o];
        float sg = 1.f / (1.f + expf(-v));
        Wb[idx] = f2bf(sg * w1[idx]);
    }
}

// h2p interior = gelu( W1A[b] (256x64) @ xT (64 x px) ); half-row (48 px) per block
__global__ __launch_bounds__(256) void k_gemm1(const u16* __restrict__ W1A, const u16* __restrict__ xT,
                                               u16* __restrict__ h2p) {
    int bi = blockIdx.x;
    int b = bi / 192, rem = bi % 192;
    int y = rem >> 1, half = rem & 1;
    int t = threadIdx.x, wave = t >> 6, lane = t & 63, l15 = lane & 15, quad = lane >> 4;
    float4x acc[4][3];
    #pragma unroll
    for (int mt = 0; mt < 4; mt++)
        #pragma unroll
        for (int nt = 0; nt < 3; nt++) acc[mt][nt] = (float4x){0.f, 0.f, 0.f, 0.f};
    const u16* Wb = W1A + b * 256 * 64;
    const u16* xb = xT + ((b * 96 + y) * 96 + half * 48) * 64;
    #pragma unroll
    for (int c0 = 0; c0 < 64; c0 += 32) {
        short8x bfr[3];
        #pragma unroll
        for (int nt = 0; nt < 3; nt++)
            bfr[nt] = *(const short8x*)(xb + (nt * 16 + l15) * 64 + c0 + quad * 8);
        #pragma unroll
        for (int mt = 0; mt < 4; mt++) {
            int oc = wave * 64 + mt * 16 + l15;
            short8x afr = *(const short8x*)(Wb + oc * 64 + c0 + quad * 8);
            #pragma unroll
            for (int nt = 0; nt < 3; nt++)
                acc[mt][nt] = __builtin_amdgcn_mfma_f32_16x16x32_bf16(afr, bfr[nt], acc[mt][nt], 0, 0, 0);
        }
    }
    const float is2 = 0.70710678118654752f;
    #pragma unroll
    for (int mt = 0; mt < 4; mt++) {
        #pragma unroll
        for (int nt = 0; nt < 3; nt++) {
            int xx = half * 48 + nt * 16 + l15;
            int oc0 = wave * 64 + mt * 16 + quad * 4;
            int g = oc0 >> 5, cl = oc0 & 31;
            u16 pk[4];
            #pragma unroll
            for (int r = 0; r < 4; r++) {
                float v = acc[mt][nt][r];
                float gl = 0.5f * v * (1.f + erff(v * is2));   // exact GELU
                pk[r] = f2bf(gl);
            }
            u16* dst = h2p + ((((b * 8 + g) * 98 + y + 1) * 98) + xx + 1) * 32 + cl;
            *(ushort4*)dst = make_ushort4(pk[0], pk[1], pk[2], pk[3]);
        }
    }
}

// partial 3x3 adaptive max pool: grid 288 = (b, k, rg); 4 rows per block
__global__ __launch_bounds__(256) void k_gl2p(const u16* __restrict__ h2p, float* __restrict__ gl2p) {
    int bi = blockIdx.x;
    int b = bi / 72, rem = bi % 72;
    int k = rem >> 3, rg = rem & 7;
    int ki = k / 3, kj = k - ki * 3;
    int t = threadIdx.x, g = t >> 5, cl = t & 31;
    const u16* plane = h2p + (b * 8 + g) * (98 * 98 * 32);
    float m = -1e30f;
    for (int r = 0; r < 4; r++) {
        int row = ki * 32 + rg * 4 + r + 1;
        const u16* base = plane + (row * 98 + kj * 32 + 1) * 32 + cl;
        #pragma unroll 4
        for (int p = 0; p < 32; p++) m = fmaxf(m, bf2f(base[p * 32]));
    }
    gl2p[((b * 9 + k) * 8 + rg) * 256 + t] = m;
}

// fc2 gating stage A: reduce gl2p, compute out2g[b][256][9], ocp2g[b][64][9]
__global__ __launch_bounds__(256) void k_gate2a(const float* __restrict__ gl2p,
                                                const float* __restrict__ ce, const float* __restrict__ gd,
                                                const float* __restrict__ gd2, const float* __restrict__ ci,
                                                float* __restrict__ out2g, float* __restrict__ ocp2g) {
    int b = blockIdx.x, t = threadIdx.x;
    __shared__ float rce[256][5];
    float gl[9], r[5];
    #pragma unroll
    for (int k = 0; k < 9; k++) {
        float m = -1e30f;
        #pragma unroll
        for (int rg = 0; rg < 8; rg++) m = fmaxf(m, gl2p[((b * 9 + k) * 8 + rg) * 256 + t]);
        gl[k] = m;
    }
    #pragma unroll
    for (int n = 0; n < 5; n++) {
        float s = 0.f;
        #pragma unroll
        for (int k = 0; k < 9; k++) s += gl[k] * ce[n * 9 + k];
        r[n] = fmaxf(s, 0.f);
        rce[t][n] = r[n];
    }
    #pragma unroll
    for (int k = 0; k < 9; k++) {
        float s = 0.f;
        #pragma unroll
        for (int n = 0; n < 5; n++) s += r[n] * gd[k * 5 + n];
        out2g[(b * 256 + t) * 9 + k] = s;
    }
    __syncthreads();
    if (t < 64) {
        int p = t >> 1, oi = t & 1;
        float rt[5];
        #pragma unroll
        for (int n = 0; n < 5; n++) {
            float s = 0.f;
            #pragma unroll
            for (int g = 0; g < 8; g++) s += rce[p * 8 + g][n] * ci[oi * 8 + g];
            rt[n] = fmaxf(s, 0.f);
        }
        #pragma unroll
        for (int k = 0; k < 9; k++) {
            float s = 0.f;
            #pragma unroll
            for (int n = 0; n < 5; n++) s += rt[n] * gd2[k * 5 + n];
            ocp2g[(b * 64 + t) * 9 + k] = s;
        }
    }
}

// fc2 gating stage B: W2A[b][g][k][oc][cl] = sigmoid(out2[c][k]+ocp2[o][k]) * w2[o][c][k]
// grid 64 = (b, slice of 16)
__global__ __launch_bounds__(256) void k_gate2b(const float* __restrict__ out2g, const float* __restrict__ ocp2g,
                                                const float* __restrict__ w2, u16* __restrict__ W2A) {
    int b = blockIdx.x >> 4, s = blockIdx.x & 15;
    int t = threadIdx.x;
    const float* o2 = out2g + b * 256 * 9;
    const float* op = ocp2g + b * 64 * 9;
    u16* Wb = W2A + b * (8 * 9 * 64 * 32);
    for (int it = 0; it < 36; it++) {
        int flat = s * 9216 + it * 256 + t;
        int cl = flat & 31;
        int o = (flat >> 5) & 63;
        int rest = flat >> 11;           // = g*9 + k
        int k = rest % 9, g = rest / 9;
        int c = g * 32 + cl;
        float v = o2[c * 9 + k] + op[o * 9 + k];
        float sg = 1.f / (1.f + expf(-v));
        Wb[flat] = f2bf(sg * w2[(o * 256 + c) * 9 + k]);
    }
}

// out[b][oc][y][x] = sum_{g,k,cl} W2A[b][g][k][oc][cl] * h2p[b][g][y+i][x+j][cl]
// one row per block; LDS-staged per c-group chunk; 4 waves: mi(2 oc-halves) x ni(2 px-halves)
__global__ __launch_bounds__(256) void k_conv2(const u16* __restrict__ W2A, const u16* __restrict__ h2p,
                                               float* __restrict__ out) {
    int b = blockIdx.x / 96, y = blockIdx.x % 96;
    int t = threadIdx.x, wave = t >> 6, lane = t & 63, l15 = lane & 15, quad = lane >> 4;
    int mi = wave & 1, ni = wave >> 1;
    __shared__ __align__(16) u16 Als[9 * 64 * 32];    // 36,864 B  [k][oc][cl]
    __shared__ __align__(16) u16 Bls[3 * 98 * 32];    // 18,816 B  [i][px][cl]
    float4x acc[2][3];
    #pragma unroll
    for (int mt = 0; mt < 2; mt++)
        #pragma unroll
        for (int nt = 0; nt < 3; nt++) acc[mt][nt] = (float4x){0.f, 0.f, 0.f, 0.f};

    for (int g = 0; g < 8; g++) {
        __syncthreads();
        // stage A chunk: 2304 x 16B, fully coalesced
        const uint4* As = (const uint4*)(W2A + (b * 8 + g) * (9 * 64 * 32));
        uint4* Ad = (uint4*)Als;
        #pragma unroll
        for (int i = 0; i < 9; i++) Ad[t + i * 256] = As[t + i * 256];
        // stage B: 3 rows x 98 px x 32c (392 x 16B per row)
        #pragma unroll
        for (int r = 0; r < 3; r++) {
            const uint4* Bs = (const uint4*)(h2p + (((b * 8 + g) * 98 + y + r) * 98) * 32);
            uint4* Bd = (uint4*)(Bls + r * 98 * 32);
            for (int i = t; i < 392; i += 256) Bd[i] = Bs[i];
        }
        __syncthreads();
        #pragma unroll
        for (int k = 0; k < 9; k++) {
            int ki = k / 3, kj = k - ki * 3;
            short8x af0 = *(const short8x*)(Als + (k * 64 + mi * 32 + l15) * 32 + quad * 8);
            short8x af1 = *(const short8x*)(Als + (k * 64 + mi * 32 + 16 + l15) * 32 + quad * 8);
            #pragma unroll
            for (int nt = 0; nt < 3; nt++) {
                int px = ni * 48 + nt * 16 + l15 + kj;
                short8x bf = *(const short8x*)(Bls + (ki * 98 + px) * 32 + quad * 8);
                acc[0][nt] = __builtin_amdgcn_mfma_f32_16x16x32_bf16(af0, bf, acc[0][nt], 0, 0, 0);
                acc[1][nt] = __builtin_amdgcn_mfma_f32_16x16x32_bf16(af1, bf, acc[1][nt], 0, 0, 0);
            }
        }
    }
    #pragma unroll
    for (int mt = 0; mt < 2; mt++) {
        #pragma unroll
        for (int nt = 0; nt < 3; nt++) {
            int xx = ni * 48 + nt * 16 + l15;
            #pragma unroll
            for (int r = 0; r < 4; r++) {
                int oc = mi * 32 + mt * 16 + quad * 4 + r;
                out[((b * 64 + oc) * 96 + y) * 96 + xx] = acc[mt][nt][r];
            }
        }
    }
}

extern "C" void kernel_launch(void* const* d_in, const int* in_sizes, int n_in,
                              void* d_out, int out_size, void* d_ws, size_t ws_size,
                              hipStream_t stream) {
    const float* x    = (const float*)d_in[0];
    const float* w1   = (const float*)d_in[1];
    const float* ce1  = (const float*)d_in[2];
    const float* gd1  = (const float*)d_in[3];
    const float* gd21 = (const float*)d_in[4];
    const float* ci1  = (const float*)d_in[5];
    const float* w2   = (const float*)d_in[6];
    const float* ce2  = (const float*)d_in[7];
    const float* gd2  = (const float*)d_in[8];
    const float* gd22 = (const float*)d_in[9];
    const float* ci2  = (const float*)d_in[10];
    float* out = (float*)d_out;

    char* ws = (char*)d_ws;
    u16*   xT    = (u16*)(ws + 0);
    float* gl2p  = (float*)(ws + 0);          // reuses xT region (dead after k_gemm1)
    float* out2g = (float*)(ws + 294912);
    float* ocp2g = (float*)(ws + 331776);
    u16*   h2p   = (u16*)(ws + 4718592);
    u16*   W1A   = (u16*)(ws + 24387584);
    u16*   W2A   = (u16*)(ws + 24518656);
    float* gl1   = (float*)(ws + 25698304);

    k_transpose<<<384, 256, 0, stream>>>(x, xT);
    k_gl1      <<<256, 256, 0, stream>>>(x, gl1);
    k_gate1    <<<4,   256, 0, stream>>>(gl1, ce1, gd1, gd21, ci1, w1, W1A);
    k_border   <<<32,  256, 0, stream>>>((u32*)h2p);
    k_gemm1    <<<768, 256, 0, stream>>>(W1A, xT, h2p);
    k_gl2p     <<<288, 256, 0, stream>>>(h2p, gl2p);
    k_gate2a   <<<4,   256, 0, stream>>>(gl2p, ce2, gd2, gd22, ci2, out2g, ocp2g);
    k_gate2b   <<<64,  256, 0, stream>>>(out2g, ocp2g, w2, W2A);
    k_conv2    <<<384, 256, 0, stream>>>(W2A, h2p, out);
}

// Round 4
// 170.391 us; speedup vs baseline: 1.6682x; 1.0538x over previous
//
#include <hip/hip_runtime.h>
#include <math.h>

typedef __attribute__((ext_vector_type(8))) short short8x;   // 8 x bf16 = 4 VGPRs
typedef __attribute__((ext_vector_type(4))) float float4x;   // MFMA 16x16 C/D frag
typedef unsigned short u16;
typedef unsigned int u32;

__device__ __forceinline__ float bf2f(u16 u) {
    return __uint_as_float(((u32)u) << 16);
}
__device__ __forceinline__ u16 f2bf(float f) {
    u32 u = __float_as_uint(f);
    u32 r = (u + 0x7fffu + ((u >> 16) & 1u)) >> 16;   // round-to-nearest-even
    return (u16)r;
}

// ---------------------------------------------------------------- sizes
// B=4, H=W=96, C_in=64, C_hid=256, C_out=64, padded HP=98. c split: 8 groups x 32.
// 5-dispatch pipeline: pre -> gate1 -> gemm1(+pool partials) -> gate2 -> conv2
// ws layout (bytes):
//   xT    @ 0         : 4*96*96*64*2  = 4,718,592  x -> bf16 c-minor [b][y][x][64]
//   h2p   @ 4718592   : 4*8*98*98*32*2= 19,668,992 bf16 [b][g][98][98][32]
//   W1A   @ 24387584  : 4*256*64*2    = 131,072    bf16 [b][oc][c64]
//   W2A   @ 24518656  : 4*8*9*64*32*2 = 1,179,648  bf16 [b][g][k][oc][c32]
//   glp1  @ 25698304  : 4*96*64*4     = 98,304     fp32 per-row channel max
//   pm    @ 25796608  : 4*96*4*256*4  = 1,572,864  fp32 pool partials [b][y][slot4][c256]

// Fused: transpose (blocks 0..383) + per-row max partials + h2p border zero (blocks 384..415)
__global__ __launch_bounds__(256) void k_pre(const float* __restrict__ x, u16* __restrict__ xT,
                                             float* __restrict__ glp1, u32* __restrict__ h2p32) {
    if (blockIdx.x >= 384) {                       // border-zero role
        u32* plane = h2p32 + (blockIdx.x - 384) * (98 * 98 * 16);
        int t = threadIdx.x;
        for (int i = t; i < 1568; i += 256) plane[i] = 0u;                  // row 0
        for (int i = t; i < 1568; i += 256) plane[97 * 98 * 16 + i] = 0u;   // row 97
        for (int i = t; i < 3072; i += 256) {                               // cols 0 & 97
            int r = (i >> 5) + 1;
            int p = ((i >> 4) & 1) * 97;
            int w = i & 15;
            plane[(r * 98 + p) * 16 + w] = 0u;
        }
        return;
    }
    int b = blockIdx.x / 96, y = blockIdx.x % 96;
    __shared__ float lds[64][97];
    const float* xr = x + ((b * 64) * 96 + y) * 96;
    for (int idx = threadIdx.x; idx < 64 * 96; idx += 256) {
        int c = idx / 96, xx = idx - c * 96;
        lds[c][xx] = xr[c * 96 * 96 + xx];
    }
    __syncthreads();
    u16* o = xT + ((b * 96 + y) * 96) * 64;
    for (int idx = threadIdx.x; idx < 96 * 64; idx += 256) {
        int xx = idx >> 6, c = idx & 63;
        o[idx] = f2bf(lds[c][xx]);
    }
    if (threadIdx.x < 64) {                        // per-row channel max
        float m = -1e30f;
        #pragma unroll 8
        for (int px = 0; px < 96; px++) m = fmaxf(m, lds[threadIdx.x][px]);
        glp1[(b * 96 + y) * 64 + threadIdx.x] = m;
    }
}

// fc1 gating -> W1A[b][oc=256][c=64]; reduces glp1 over rows first
__global__ __launch_bounds__(256) void k_gate1(const float* __restrict__ glp1,
                                               const float* __restrict__ ce, const float* __restrict__ gd,
                                               const float* __restrict__ gd2, const float* __restrict__ ci,
                                               const float* __restrict__ w1, u16* __restrict__ W1A) {
    int b = blockIdx.x, t = threadIdx.x;
    __shared__ float rce[64], out1[64], ocp[256];
    float cew = ce[0], gdw = gd[0], gd2w = gd2[0];
    if (t < 64) {
        float m = -1e30f;
        for (int y = 0; y < 96; y++) m = fmaxf(m, glp1[(b * 96 + y) * 64 + t]);
        float r = fmaxf(m * cew, 0.f);
        rce[t] = r;
        out1[t] = r * gdw;
    }
    __syncthreads();
    {
        int p = t >> 5, oi = t & 31;
        float s = 0.f;
        #pragma unroll
        for (int g = 0; g < 8; g++) s += rce[p * 8 + g] * ci[oi * 8 + g];
        ocp[t] = fmaxf(s, 0.f) * gd2w;
    }
    __syncthreads();
    u16* Wb = W1A + b * 256 * 64;
    for (int idx = t; idx < 256 * 64; idx += 256) {
        int o = idx >> 6, c = idx & 63;
        float v = out1[c] + ocp[o];
        float sg = 1.f / (1.f + expf(-v));
        Wb[idx] = f2bf(sg * w1[idx]);
    }
}

// h2p interior = gelu( W1A[b] (256x64) @ xT (64 x px) ); half-row (48 px) per block.
// Epilogue also emits 3x3-pool partial maxes: pm[b][y][slot][c], slots:
//   half0: slot0 = max(px0..31) [bin0], slot1 = max(px32..47) [bin1 part]
//   half1: slot2 = max(px48..63) [bin1 part], slot3 = max(px64..95) [bin2]
__global__ __launch_bounds__(256) void k_gemm1(const u16* __restrict__ W1A, const u16* __restrict__ xT,
                                               u16* __restrict__ h2p, float* __restrict__ pm) {
    int bi = blockIdx.x;
    int b = bi / 192, rem = bi % 192;
    int y = rem >> 1, half = rem & 1;
    int t = threadIdx.x, wave = t >> 6, lane = t & 63, l15 = lane & 15, quad = lane >> 4;
    float4x acc[4][3];
    #pragma unroll
    for (int mt = 0; mt < 4; mt++)
        #pragma unroll
        for (int nt = 0; nt < 3; nt++) acc[mt][nt] = (float4x){0.f, 0.f, 0.f, 0.f};
    const u16* Wb = W1A + b * 256 * 64;
    const u16* xb = xT + ((b * 96 + y) * 96 + half * 48) * 64;
    #pragma unroll
    for (int c0 = 0; c0 < 64; c0 += 32) {
        short8x bfr[3];
        #pragma unroll
        for (int nt = 0; nt < 3; nt++)
            bfr[nt] = *(const short8x*)(xb + (nt * 16 + l15) * 64 + c0 + quad * 8);
        #pragma unroll
        for (int mt = 0; mt < 4; mt++) {
            int oc = wave * 64 + mt * 16 + l15;
            short8x afr = *(const short8x*)(Wb + oc * 64 + c0 + quad * 8);
            #pragma unroll
            for (int nt = 0; nt < 3; nt++)
                acc[mt][nt] = __builtin_amdgcn_mfma_f32_16x16x32_bf16(afr, bfr[nt], acc[mt][nt], 0, 0, 0);
        }
    }
    const float is2 = 0.70710678118654752f;
    float gf[4][3][4];
    #pragma unroll
    for (int mt = 0; mt < 4; mt++) {
        #pragma unroll
        for (int nt = 0; nt < 3; nt++) {
            int xx = half * 48 + nt * 16 + l15;
            int oc0 = wave * 64 + mt * 16 + quad * 4;
            int g = oc0 >> 5, cl = oc0 & 31;
            u16 pk[4];
            #pragma unroll
            for (int r = 0; r < 4; r++) {
                float v = acc[mt][nt][r];
                float gl = 0.5f * v * (1.f + erff(v * is2));   // exact GELU
                gf[mt][nt][r] = gl;
                pk[r] = f2bf(gl);
            }
            u16* dst = h2p + ((((b * 8 + g) * 98 + y + 1) * 98) + xx + 1) * 32 + cl;
            *(ushort4*)dst = make_ushort4(pk[0], pk[1], pk[2], pk[3]);
        }
    }
    // pool partials: reduce over the 16 px lanes (l15) via butterfly shuffles
    #pragma unroll
    for (int mt = 0; mt < 4; mt++) {
        float vA[4], vB[4];
        #pragma unroll
        for (int r = 0; r < 4; r++) {
            if (half == 0) { vA[r] = fmaxf(gf[mt][0][r], gf[mt][1][r]); vB[r] = gf[mt][2][r]; }
            else           { vA[r] = gf[mt][0][r]; vB[r] = fmaxf(gf[mt][1][r], gf[mt][2][r]); }
        }
        #pragma unroll
        for (int m = 1; m < 16; m <<= 1) {
            #pragma unroll
            for (int r = 0; r < 4; r++) {
                vA[r] = fmaxf(vA[r], __shfl_xor(vA[r], m));
                vB[r] = fmaxf(vB[r], __shfl_xor(vB[r], m));
            }
        }
        if (l15 == 0) {
            float* base = pm + ((b * 96 + y) * 4 + half * 2) * 256;
            #pragma unroll
            for (int r = 0; r < 4; r++) {
                int oc = wave * 64 + mt * 16 + quad * 4 + r;
                base[oc] = vA[r];
                base[256 + oc] = vB[r];
            }
        }
    }
}

// Fused fc2 gating: each of 64 blocks (b,slice) reduces pm -> gl, computes out2/ocp2
// in shared (redundantly per block), writes its W2A slice.
// W2A[b][g][k][oc][cl] = sigmoid(out2[c][k]+ocp2[o][k]) * w2[o][c][k]
__global__ __launch_bounds__(256) void k_gate2(const float* __restrict__ pm,
                                               const float* __restrict__ ce, const float* __restrict__ gd,
                                               const float* __restrict__ gd2, const float* __restrict__ ci,
                                               const float* __restrict__ w2, u16* __restrict__ W2A) {
    int b = blockIdx.x >> 4, s = blockIdx.x & 15;
    int t = threadIdx.x;
    __shared__ float rce[256][5];
    __shared__ float out2[256][9];
    __shared__ float ocp2[64][9];
    {
        float gl[9];
        #pragma unroll
        for (int ki = 0; ki < 3; ki++) {
            float b0 = -1e30f, b1 = -1e30f, b2 = -1e30f;
            for (int yy = 0; yy < 32; yy++) {
                const float* p = pm + ((b * 96 + ki * 32 + yy) * 4) * 256 + t;
                b0 = fmaxf(b0, p[0]);
                b1 = fmaxf(b1, fmaxf(p[256], p[512]));
                b2 = fmaxf(b2, p[768]);
            }
            gl[ki * 3 + 0] = b0; gl[ki * 3 + 1] = b1; gl[ki * 3 + 2] = b2;
        }
        float r[5];
        #pragma unroll
        for (int n = 0; n < 5; n++) {
            float sv = 0.f;
            #pragma unroll
            for (int k = 0; k < 9; k++) sv += gl[k] * ce[n * 9 + k];
            r[n] = fmaxf(sv, 0.f);
            rce[t][n] = r[n];
        }
        #pragma unroll
        for (int k = 0; k < 9; k++) {
            float sv = 0.f;
            #pragma unroll
            for (int n = 0; n < 5; n++) sv += r[n] * gd[k * 5 + n];
            out2[t][k] = sv;
        }
    }
    __syncthreads();
    if (t < 64) {
        int p = t >> 1, oi = t & 1;
        float rt[5];
        #pragma unroll
        for (int n = 0; n < 5; n++) {
            float sv = 0.f;
            #pragma unroll
            for (int g = 0; g < 8; g++) sv += rce[p * 8 + g][n] * ci[oi * 8 + g];
            rt[n] = fmaxf(sv, 0.f);
        }
        #pragma unroll
        for (int k = 0; k < 9; k++) {
            float sv = 0.f;
            #pragma unroll
            for (int n = 0; n < 5; n++) sv += rt[n] * gd2[k * 5 + n];
            ocp2[t][k] = sv;
        }
    }
    __syncthreads();
    u16* Wb = W2A + b * (8 * 9 * 64 * 32);
    for (int it = 0; it < 36; it++) {
        int flat = s * 9216 + it * 256 + t;
        int cl = flat & 31;
        int o = (flat >> 5) & 63;
        int rest = flat >> 11;           // = g*9 + k
        int k = rest % 9, g = rest / 9;
        int c = g * 32 + cl;
        float v = out2[c][k] + ocp2[o][k];
        float sg = 1.f / (1.f + expf(-v));
        Wb[flat] = f2bf(sg * w2[(o * 256 + c) * 9 + k]);
    }
}

// out[b][oc][y][x] = sum_{g,k,cl} W2A[b][g][k][oc][cl] * h2p[b][g][y+i][x+j][cl]
// one row per block; LDS-staged per c-group chunk; 4 waves: mi(2 oc-halves) x ni(2 px-halves)
__global__ __launch_bounds__(256) void k_conv2(const u16* __restrict__ W2A, const u16* __restrict__ h2p,
                                               float* __restrict__ out) {
    int b = blockIdx.x / 96, y = blockIdx.x % 96;
    int t = threadIdx.x, wave = t >> 6, lane = t & 63, l15 = lane & 15, quad = lane >> 4;
    int mi = wave & 1, ni = wave >> 1;
    __shared__ __align__(16) u16 Als[9 * 64 * 32];    // 36,864 B  [k][oc][cl]
    __shared__ __align__(16) u16 Bls[3 * 98 * 32];    // 18,816 B  [i][px][cl]
    float4x acc[2][3];
    #pragma unroll
    for (int mt = 0; mt < 2; mt++)
        #pragma unroll
        for (int nt = 0; nt < 3; nt++) acc[mt][nt] = (float4x){0.f, 0.f, 0.f, 0.f};

    for (int g = 0; g < 8; g++) {
        __syncthreads();
        // stage A chunk: 2304 x 16B, fully coalesced
        const uint4* As = (const uint4*)(W2A + (b * 8 + g) * (9 * 64 * 32));
        uint4* Ad = (uint4*)Als;
        #pragma unroll
        for (int i = 0; i < 9; i++) Ad[t + i * 256] = As[t + i * 256];
        // stage B: 3 rows x 98 px x 32c (392 x 16B per row)
        #pragma unroll
        for (int r = 0; r < 3; r++) {
            const uint4* Bs = (const uint4*)(h2p + (((b * 8 + g) * 98 + y + r) * 98) * 32);
            uint4* Bd = (uint4*)(Bls + r * 98 * 32);
            for (int i = t; i < 392; i += 256) Bd[i] = Bs[i];
        }
        __syncthreads();
        #pragma unroll
        for (int k = 0; k < 9; k++) {
            int ki = k / 3, kj = k - ki * 3;
            short8x af0 = *(const short8x*)(Als + (k * 64 + mi * 32 + l15) * 32 + quad * 8);
            short8x af1 = *(const short8x*)(Als + (k * 64 + mi * 32 + 16 + l15) * 32 + quad * 8);
            #pragma unroll
            for (int nt = 0; nt < 3; nt++) {
                int px = ni * 48 + nt * 16 + l15 + kj;
                short8x bf = *(const short8x*)(Bls + (ki * 98 + px) * 32 + quad * 8);
                acc[0][nt] = __builtin_amdgcn_mfma_f32_16x16x32_bf16(af0, bf, acc[0][nt], 0, 0, 0);
                acc[1][nt] = __builtin_amdgcn_mfma_f32_16x16x32_bf16(af1, bf, acc[1][nt], 0, 0, 0);
            }
        }
    }
    #pragma unroll
    for (int mt = 0; mt < 2; mt++) {
        #pragma unroll
        for (int nt = 0; nt < 3; nt++) {
            int xx = ni * 48 + nt * 16 + l15;
            #pragma unroll
            for (int r = 0; r < 4; r++) {
                int oc = mi * 32 + mt * 16 + quad * 4 + r;
                out[((b * 64 + oc) * 96 + y) * 96 + xx] = acc[mt][nt][r];
            }
        }
    }
}

extern "C" void kernel_launch(void* const* d_in, const int* in_sizes, int n_in,
                              void* d_out, int out_size, void* d_ws, size_t ws_size,
                              hipStream_t stream) {
    const float* x    = (const float*)d_in[0];
    const float* w1   = (const float*)d_in[1];
    const float* ce1  = (const float*)d_in[2];
    const float* gd1  = (const float*)d_in[3];
    const float* gd21 = (const float*)d_in[4];
    const float* ci1  = (const float*)d_in[5];
    const float* w2   = (const float*)d_in[6];
    const float* ce2  = (const float*)d_in[7];
    const float* gd2  = (const float*)d_in[8];
    const float* gd22 = (const float*)d_in[9];
    const float* ci2  = (const float*)d_in[10];
    float* out = (float*)d_out;

    char* ws = (char*)d_ws;
    u16*   xT   = (u16*)(ws + 0);
    u16*   h2p  = (u16*)(ws + 4718592);
    u16*   W1A  = (u16*)(ws + 24387584);
    u16*   W2A  = (u16*)(ws + 24518656);
    float* glp1 = (float*)(ws + 25698304);
    float* pm   = (float*)(ws + 25796608);

    k_pre  <<<416, 256, 0, stream>>>(x, xT, glp1, (u32*)h2p);
    k_gate1<<<4,   256, 0, stream>>>(glp1, ce1, gd1, gd21, ci1, w1, W1A);
    k_gemm1<<<768, 256, 0, stream>>>(W1A, xT, h2p, pm);
    k_gate2<<<64,  256, 0, stream>>>(pm, ce2, gd2, gd22, ci2, w2, W2A);
    k_conv2<<<384, 256, 0, stream>>>(W2A, h2p, out);
}

// Round 6
// 149.840 us; speedup vs baseline: 1.8970x; 1.1372x over previous
//
#include <hip/hip_runtime.h>
#include <math.h>

typedef __attribute__((ext_vector_type(8))) short short8x;   // 8 x bf16 = 4 VGPRs
typedef __attribute__((ext_vector_type(4))) float float4x;   // MFMA 16x16 C/D frag
typedef unsigned short u16;
typedef unsigned int u32;

__device__ __forceinline__ float bf2f(u16 u) {
    return __uint_as_float(((u32)u) << 16);
}
__device__ __forceinline__ u16 f2bf(float f) {
    u32 u = __float_as_uint(f);
    u32 r = (u + 0x7fffu + ((u >> 16) & 1u)) >> 16;   // round-to-nearest-even
    return (u16)r;
}

// ---------------------------------------------------------------- sizes
// B=4, H=W=96, C_in=64, C_hid=256, C_out=64, padded HP=98. c split: 8 groups x 32.
// 5-dispatch pipeline: gl1(+border) -> gate1 -> gemm1(fused x-stage + pool partials)
//                      -> gate2 -> conv2
// NOTE: h2p border-zero MUST be in an earlier dispatch than gemm1's interior
// writes: border px0/px97 cells share 128B L2 lines with interior px1/px96 cells;
// concurrent cross-block writes to the same line (round 5) failed the replay
// tripwire; dispatch-serialized (rounds 2-4 pattern) passes.
// ws layout (bytes):
//   h2p   @ 4718592   : 4*8*98*98*32*2= 19,668,992 bf16 [b][g][98][98][32]
//   W1A   @ 24387584  : 4*256*64*2    = 131,072    bf16 [b][oc][c64]
//   W2A   @ 24518656  : 4*8*9*64*32*2 = 1,179,648  bf16 [b][g][k][oc][c32]
//   gl1   @ 25698304  : 4*64*4       = 1,024       fp32 per-(b,c) global max
//   pm    @ 25796608  : 4*96*4*256*4  = 1,572,864  fp32 pool partials [b][y][slot4][c256]

// blocks 0..255: global max over image per (b,c); blocks 256..287: h2p border zero
__global__ __launch_bounds__(256) void k_gl1(const float* __restrict__ x, float* __restrict__ gl1,
                                             u32* __restrict__ h2p32) {
    if (blockIdx.x >= 256) {                        // border-zero duty (plane bi)
        int t = threadIdx.x;
        u32* plane = h2p32 + (blockIdx.x - 256) * (98 * 98 * 16);
        for (int i = t; i < 1568; i += 256) plane[i] = 0u;                  // row 0
        for (int i = t; i < 1568; i += 256) plane[97 * 98 * 16 + i] = 0u;   // row 97
        for (int i = t; i < 3072; i += 256) {                               // cols 0 & 97
            int r = (i >> 5) + 1;
            int p = ((i >> 4) & 1) * 97;
            int w = i & 15;
            plane[(r * 98 + p) * 16 + w] = 0u;
        }
        return;
    }
    int b = blockIdx.x >> 6, c = blockIdx.x & 63;
    const float4* p = (const float4*)(x + (b * 64 + c) * 9216);
    float m = -1e30f;
    #pragma unroll
    for (int i = 0; i < 9; i++) {
        float4 v = p[i * 256 + threadIdx.x];
        m = fmaxf(m, fmaxf(fmaxf(v.x, v.y), fmaxf(v.z, v.w)));
    }
    __shared__ float red[256];
    red[threadIdx.x] = m;
    __syncthreads();
    for (int s = 128; s > 0; s >>= 1) {
        if (threadIdx.x < s) red[threadIdx.x] = fmaxf(red[threadIdx.x], red[threadIdx.x + s]);
        __syncthreads();
    }
    if (threadIdx.x == 0) gl1[b * 64 + c] = red[0];
}

// fc1 gating -> W1A[b][oc=256][c=64]
__global__ __launch_bounds__(256) void k_gate1(const float* __restrict__ gl1,
                                               const float* __restrict__ ce, const float* __restrict__ gd,
                                               const float* __restrict__ gd2, const float* __restrict__ ci,
                                               const float* __restrict__ w1, u16* __restrict__ W1A) {
    int b = blockIdx.x, t = threadIdx.x;
    __shared__ float rce[64], out1[64], ocp[256];
    float cew = ce[0], gdw = gd[0], gd2w = gd2[0];
    if (t < 64) {
        float r = fmaxf(gl1[b * 64 + t] * cew, 0.f);
        rce[t] = r;
        out1[t] = r * gdw;
    }
    __syncthreads();
    {
        int p = t >> 5, oi = t & 31;
        float s = 0.f;
        #pragma unroll
        for (int g = 0; g < 8; g++) s += rce[p * 8 + g] * ci[oi * 8 + g];
        ocp[t] = fmaxf(s, 0.f) * gd2w;
    }
    __syncthreads();
    u16* Wb = W1A + b * 256 * 64;
    for (int idx = t; idx < 256 * 64; idx += 256) {
        int o = idx >> 6, c = idx & 63;
        float v = out1[c] + ocp[o];
        float sg = 1.f / (1.f + expf(-v));
        Wb[idx] = f2bf(sg * w1[idx]);
    }
}

// h2p interior = gelu( W1A[b] (256x64) @ x-slab (64 x 48px) ); half-row per block.
// Fused: x load+transpose via LDS slab (xs[48][72]); pool partials pm[b][y][slot][c].
__global__ __launch_bounds__(256) void k_gemm1(const u16* __restrict__ W1A, const float* __restrict__ x,
                                               u16* __restrict__ h2p, float* __restrict__ pm) {
    int bi = blockIdx.x;
    int b = bi / 192, rem = bi % 192;
    int y = rem >> 1, half = rem & 1;
    int t = threadIdx.x, wave = t >> 6, lane = t & 63, l15 = lane & 15, quad = lane >> 4;

    __shared__ __align__(16) u16 xs[48 * 72];       // [px][c], row pad 72 (144 B, 16B-mult)
    const float* xb = x + (b * 64) * 9216 + y * 96 + half * 48;
    #pragma unroll
    for (int i = 0; i < 12; i++) {
        int idx = i * 256 + t;                      // 3072 = 64c x 48px
        int c = idx / 48, px = idx - c * 48;
        xs[px * 72 + c] = f2bf(xb[c * 9216 + px]);
    }
    __syncthreads();

    float4x acc[4][3];
    #pragma unroll
    for (int mt = 0; mt < 4; mt++)
        #pragma unroll
        for (int nt = 0; nt < 3; nt++) acc[mt][nt] = (float4x){0.f, 0.f, 0.f, 0.f};
    const u16* Wb = W1A + b * 256 * 64;
    #pragma unroll
    for (int c0 = 0; c0 < 64; c0 += 32) {
        short8x bfr[3];
        #pragma unroll
        for (int nt = 0; nt < 3; nt++)
            bfr[nt] = *(const short8x*)(xs + (nt * 16 + l15) * 72 + c0 + quad * 8);
        #pragma unroll
        for (int mt = 0; mt < 4; mt++) {
            int oc = wave * 64 + mt * 16 + l15;
            short8x afr = *(const short8x*)(Wb + oc * 64 + c0 + quad * 8);
            #pragma unroll
            for (int nt = 0; nt < 3; nt++)
                acc[mt][nt] = __builtin_amdgcn_mfma_f32_16x16x32_bf16(afr, bfr[nt], acc[mt][nt], 0, 0, 0);
        }
    }
    const float is2 = 0.70710678118654752f;
    float gf[4][3][4];
    #pragma unroll
    for (int mt = 0; mt < 4; mt++) {
        #pragma unroll
        for (int nt = 0; nt < 3; nt++) {
            int xx = half * 48 + nt * 16 + l15;
            int oc0 = wave * 64 + mt * 16 + quad * 4;
            int g = oc0 >> 5, cl = oc0 & 31;
            u16 pk[4];
            #pragma unroll
            for (int r = 0; r < 4; r++) {
                float v = acc[mt][nt][r];
                float gl = 0.5f * v * (1.f + erff(v * is2));   // exact GELU
                gf[mt][nt][r] = gl;
                pk[r] = f2bf(gl);
            }
            u16* dst = h2p + ((((b * 8 + g) * 98 + y + 1) * 98) + xx + 1) * 32 + cl;
            *(ushort4*)dst = make_ushort4(pk[0], pk[1], pk[2], pk[3]);
        }
    }
    // pool partials: reduce over the 16 px lanes (l15) via butterfly shuffles
    // half0: slotA = max(px0..31), slotB = max(px32..47); half1: slotA = max(px48..63), slotB = max(px64..95)
    #pragma unroll
    for (int mt = 0; mt < 4; mt++) {
        float vA[4], vB[4];
        #pragma unroll
        for (int r = 0; r < 4; r++) {
            if (half == 0) { vA[r] = fmaxf(gf[mt][0][r], gf[mt][1][r]); vB[r] = gf[mt][2][r]; }
            else           { vA[r] = gf[mt][0][r]; vB[r] = fmaxf(gf[mt][1][r], gf[mt][2][r]); }
        }
        #pragma unroll
        for (int m = 1; m < 16; m <<= 1) {
            #pragma unroll
            for (int r = 0; r < 4; r++) {
                vA[r] = fmaxf(vA[r], __shfl_xor(vA[r], m));
                vB[r] = fmaxf(vB[r], __shfl_xor(vB[r], m));
            }
        }
        if (l15 == 0) {
            float* base = pm + ((b * 96 + y) * 4 + half * 2) * 256;
            #pragma unroll
            for (int r = 0; r < 4; r++) {
                int oc = wave * 64 + mt * 16 + quad * 4 + r;
                base[oc] = vA[r];
                base[256 + oc] = vB[r];
            }
        }
    }
}

// Fused fc2 gating: each of 64 blocks (b,slice) reduces pm -> gl, computes out2/ocp2
// (redundantly per block), writes its W2A slice.
__global__ __launch_bounds__(256) void k_gate2(const float* __restrict__ pm,
                                               const float* __restrict__ ce, const float* __restrict__ gd,
                                               const float* __restrict__ gd2, const float* __restrict__ ci,
                                               const float* __restrict__ w2, u16* __restrict__ W2A) {
    int b = blockIdx.x >> 4, s = blockIdx.x & 15;
    int t = threadIdx.x;
    __shared__ float rce[256][5];
    __shared__ float out2[256][9];
    __shared__ float ocp2[64][9];
    {
        float gl[9];
        #pragma unroll
        for (int ki = 0; ki < 3; ki++) {
            float b0 = -1e30f, b1 = -1e30f, b2 = -1e30f;
            for (int yy = 0; yy < 32; yy++) {
                const float* p = pm + ((b * 96 + ki * 32 + yy) * 4) * 256 + t;
                b0 = fmaxf(b0, p[0]);
                b1 = fmaxf(b1, fmaxf(p[256], p[512]));
                b2 = fmaxf(b2, p[768]);
            }
            gl[ki * 3 + 0] = b0; gl[ki * 3 + 1] = b1; gl[ki * 3 + 2] = b2;
        }
        float r[5];
        #pragma unroll
        for (int n = 0; n < 5; n++) {
            float sv = 0.f;
            #pragma unroll
            for (int k = 0; k < 9; k++) sv += gl[k] * ce[n * 9 + k];
            r[n] = fmaxf(sv, 0.f);
            rce[t][n] = r[n];
        }
        #pragma unroll
        for (int k = 0; k < 9; k++) {
            float sv = 0.f;
            #pragma unroll
            for (int n = 0; n < 5; n++) sv += r[n] * gd[k * 5 + n];
            out2[t][k] = sv;
        }
    }
    __syncthreads();
    if (t < 64) {
        int p = t >> 1, oi = t & 1;
        float rt[5];
        #pragma unroll
        for (int n = 0; n < 5; n++) {
            float sv = 0.f;
            #pragma unroll
            for (int g = 0; g < 8; g++) sv += rce[p * 8 + g][n] * ci[oi * 8 + g];
            rt[n] = fmaxf(sv, 0.f);
        }
        #pragma unroll
        for (int k = 0; k < 9; k++) {
            float sv = 0.f;
            #pragma unroll
            for (int n = 0; n < 5; n++) sv += rt[n] * gd2[k * 5 + n];
            ocp2[t][k] = sv;
        }
    }
    __syncthreads();
    u16* Wb = W2A + b * (8 * 9 * 64 * 32);
    for (int it = 0; it < 36; it++) {
        int flat = s * 9216 + it * 256 + t;
        int cl = flat & 31;
        int o = (flat >> 5) & 63;
        int rest = flat >> 11;           // = g*9 + k
        int k = rest % 9, g = rest / 9;
        int c = g * 32 + cl;
        float v = out2[c][k] + ocp2[o][k];
        float sg = 1.f / (1.f + expf(-v));
        Wb[flat] = f2bf(sg * w2[(o * 256 + c) * 9 + k]);
    }
}

// out[b][oc][y][x] = sum_{g,k,cl} W2A[b][g][k][oc][cl] * h2p[b][g][y+i][x+j][cl]
// one row per block; LDS-staged per c-group chunk; 4 waves: mi(2 oc-halves) x ni(2 px-halves)
__global__ __launch_bounds__(256) void k_conv2(const u16* __restrict__ W2A, const u16* __restrict__ h2p,
                                               float* __restrict__ out) {
    int b = blockIdx.x / 96, y = blockIdx.x % 96;
    int t = threadIdx.x, wave = t >> 6, lane = t & 63, l15 = lane & 15, quad = lane >> 4;
    int mi = wave & 1, ni = wave >> 1;
    __shared__ __align__(16) u16 Als[9 * 64 * 32];    // 36,864 B  [k][oc][cl]
    __shared__ __align__(16) u16 Bls[3 * 98 * 32];    // 18,816 B  [i][px][cl]
    float4x acc[2][3];
    #pragma unroll
    for (int mt = 0; mt < 2; mt++)
        #pragma unroll
        for (int nt = 0; nt < 3; nt++) acc[mt][nt] = (float4x){0.f, 0.f, 0.f, 0.f};

    for (int g = 0; g < 8; g++) {
        __syncthreads();
        const uint4* As = (const uint4*)(W2A + (b * 8 + g) * (9 * 64 * 32));
        uint4* Ad = (uint4*)Als;
        #pragma unroll
        for (int i = 0; i < 9; i++) Ad[t + i * 256] = As[t + i * 256];
        #pragma unroll
        for (int r = 0; r < 3; r++) {
            const uint4* Bs = (const uint4*)(h2p + (((b * 8 + g) * 98 + y + r) * 98) * 32);
            uint4* Bd = (uint4*)(Bls + r * 98 * 32);
            for (int i = t; i < 392; i += 256) Bd[i] = Bs[i];
        }
        __syncthreads();
        #pragma unroll
        for (int k = 0; k < 9; k++) {
            int ki = k / 3, kj = k - ki * 3;
            short8x af0 = *(const short8x*)(Als + (k * 64 + mi * 32 + l15) * 32 + quad * 8);
            short8x af1 = *(const short8x*)(Als + (k * 64 + mi * 32 + 16 + l15) * 32 + quad * 8);
            #pragma unroll
            for (int nt = 0; nt < 3; nt++) {
                int px = ni * 48 + nt * 16 + l15 + kj;
                short8x bf = *(const short8x*)(Bls + (ki * 98 + px) * 32 + quad * 8);
                acc[0][nt] = __builtin_amdgcn_mfma_f32_16x16x32_bf16(af0, bf, acc[0][nt], 0, 0, 0);
                acc[1][nt] = __builtin_amdgcn_mfma_f32_16x16x32_bf16(af1, bf, acc[1][nt], 0, 0, 0);
            }
        }
    }
    #pragma unroll
    for (int mt = 0; mt < 2; mt++) {
        #pragma unroll
        for (int nt = 0; nt < 3; nt++) {
            int xx = ni * 48 + nt * 16 + l15;
            #pragma unroll
            for (int r = 0; r < 4; r++) {
                int oc = mi * 32 + mt * 16 + quad * 4 + r;
                out[((b * 64 + oc) * 96 + y) * 96 + xx] = acc[mt][nt][r];
            }
        }
    }
}

extern "C" void kernel_launch(void* const* d_in, const int* in_sizes, int n_in,
                              void* d_out, int out_size, void* d_ws, size_t ws_size,
                              hipStream_t stream) {
    const float* x    = (const float*)d_in[0];
    const float* w1   = (const float*)d_in[1];
    const float* ce1  = (const float*)d_in[2];
    const float* gd1  = (const float*)d_in[3];
    const float* gd21 = (const float*)d_in[4];
    const float* ci1  = (const float*)d_in[5];
    const float* w2   = (const float*)d_in[6];
    const float* ce2  = (const float*)d_in[7];
    const float* gd2  = (const float*)d_in[8];
    const float* gd22 = (const float*)d_in[9];
    const float* ci2  = (const float*)d_in[10];
    float* out = (float*)d_out;

    char* ws = (char*)d_ws;
    u16*   h2p  = (u16*)(ws + 4718592);
    u16*   W1A  = (u16*)(ws + 24387584);
    u16*   W2A  = (u16*)(ws + 24518656);
    float* gl1  = (float*)(ws + 25698304);
    float* pm   = (float*)(ws + 25796608);

    k_gl1  <<<288, 256, 0, stream>>>(x, gl1, (u32*)h2p);
    k_gate1<<<4,   256, 0, stream>>>(gl1, ce1, gd1, gd21, ci1, w1, W1A);
    k_gemm1<<<768, 256, 0, stream>>>(W1A, x, h2p, pm);
    k_gate2<<<64,  256, 0, stream>>>(pm, ce2, gd2, gd22, ci2, w2, W2A);
    k_conv2<<<384, 256, 0, stream>>>(W2A, h2p, out);
}